// Round 4
// baseline (340.709 us; speedup 1.0000x reference)
//
#include <hip/hip_runtime.h>
#include <hip/hip_bf16.h>
#include <math.h>

// Cosine attention, n=8, L=S=2048, d=v=64.
// out0 = softmax((q^·k^T)/8) @ V  [8,2048,64]; out1 = softmax scores [8,2048,2048]
// |score| <= 1/8 (unit vectors) -> exp in [0.88,1.13] -> no max subtraction.
// Normalization linear -> PV on unnormalized exp, scaled at end.
// R3 post-mortem: barrier-per-chunk was the latency bottleneck (4 coupled
// waves x 4 blocks/CU). v2: each wave owns 16 L-rows x private 512-col
// S-strip -> barrier-free hot loop, wave-private LDS bounce. Plain stores
// (nontemporal amplified WRITE_SIZE 141->171 MB).

typedef __bf16 bf16x8 __attribute__((ext_vector_type(8)));
typedef __bf16 bf16x4 __attribute__((ext_vector_type(4)));
typedef float f32x4 __attribute__((ext_vector_type(4)));

#define NB 8
#define LL 2048
#define SS 2048
#define DD 64
#define WORDS (SS / 32)  // 64 u32 bitmask words per row
#define STRIP 512        // s-cols per wave

// ---- prep 0: pack int32 mask -> bitmask ----
__global__ __launch_bounds__(256) void pack_mask(const int* __restrict__ mask,
                                                 unsigned long long* __restrict__ bm) {
  const int w = threadIdx.x >> 6, lane = threadIdx.x & 63;
  const size_t gw = (size_t)blockIdx.x * 4 + w;
  const size_t stride = (size_t)gridDim.x * 4;
#pragma unroll
  for (int i = 0; i < 4; ++i) {
    size_t seg = gw + (size_t)i * stride;
    int m = __builtin_nontemporal_load(mask + seg * 64 + lane);
    unsigned long long b = __ballot(m != 0);
    if (lane == 0) bm[seg] = b;
  }
}

// ---- prep 1: L2-normalize Q (fold 1/8) and K rows, cast to bf16 ----
__global__ __launch_bounds__(256) void prep_norm(const float* __restrict__ q,
                                                 const float* __restrict__ k,
                                                 __bf16* __restrict__ Qb,
                                                 __bf16* __restrict__ Kb) {
  int w = threadIdx.x >> 6, lane = threadIdx.x & 63;
  int r = blockIdx.x * 4 + w;
  const float* src;
  __bf16* dst;
  float extra;
  if (r < NB * LL) {
    src = q + (size_t)r * DD;
    dst = Qb + (size_t)r * DD;
    extra = 0.125f;
  } else {
    int rk = r - NB * LL;
    src = k + (size_t)rk * DD;
    dst = Kb + (size_t)rk * DD;
    extra = 1.0f;
  }
  float x = src[lane];
  float ss = x * x;
  ss += __shfl_xor(ss, 1);
  ss += __shfl_xor(ss, 2);
  ss += __shfl_xor(ss, 4);
  ss += __shfl_xor(ss, 8);
  ss += __shfl_xor(ss, 16);
  ss += __shfl_xor(ss, 32);
  float nrm = sqrtf(ss);
  float sc = extra / fmaxf(nrm, 1e-12f);
  dst[lane] = (__bf16)(x * sc);
}

// ---- prep 2: V [n][s][v] f32 -> Vt [n][v][s] bf16 ----
__global__ __launch_bounds__(256) void prep_vt(const float* __restrict__ v,
                                               __bf16* __restrict__ Vt) {
  __shared__ __bf16 tile[64][72];
  int n = blockIdx.y;
  int s0 = blockIdx.x * 64;
  int t = threadIdx.x;
#pragma unroll
  for (int it = 0; it < 4; ++it) {
    int idx = t + it * 256;
    int s = idx >> 4, c = idx & 15;
    float4 f = *(const float4*)(v + ((size_t)(n * SS + s0 + s)) * DD + c * 4);
    tile[s][c * 4 + 0] = (__bf16)f.x;
    tile[s][c * 4 + 1] = (__bf16)f.y;
    tile[s][c * 4 + 2] = (__bf16)f.z;
    tile[s][c * 4 + 3] = (__bf16)f.w;
  }
  __syncthreads();
#pragma unroll
  for (int it = 0; it < 4; ++it) {
    int idx = t + it * 256;
    int vv = idx >> 4, c = idx & 15;
    bf16x4 o;
    o[0] = tile[c * 4 + 0][vv];
    o[1] = tile[c * 4 + 1][vv];
    o[2] = tile[c * 4 + 2][vv];
    o[3] = tile[c * 4 + 3][vv];
    *(bf16x4*)(Vt + ((size_t)(n * DD + vv)) * SS + s0 + c * 4) = o;
  }
}

// ---- main v2: 16 L-rows/block; wave w owns s-strip [512w, 512w+512) ----
// Hot loop is barrier-free: wave-private LDS bounce for the C/D->A transform.
// LDS map (bytes): [0,18432) e_lds[4][2][16][72] bf16  (aliased by o_lds[4][16][64] f32 after pass A)
//                  [18432,22528) bm_t[64][16] u32
//                  [22528,22784) rs_lds[4][16] f32
__global__ __launch_bounds__(256, 4) void attn_main(const __bf16* __restrict__ Qb,
                                                    const __bf16* __restrict__ Kb,
                                                    const __bf16* __restrict__ Vt,
                                                    const unsigned* __restrict__ bm32,
                                                    float* __restrict__ out_val,
                                                    float* __restrict__ out_score) {
  __shared__ char smem[22784];
  __bf16(*e_lds)[2][16][72] = (__bf16(*)[2][16][72])smem;
  unsigned(*bm_t)[16] = (unsigned(*)[16])(smem + 18432);
  float(*rs_lds)[16] = (float(*)[16])(smem + 22528);
  float(*o_lds)[16][64] = (float(*)[16][64])smem;  // alias of e_lds (after barrier)

  const int n = blockIdx.y;
  const int l0 = blockIdx.x * 16;
  const int t = threadIdx.x;
  const int w = t >> 6;
  const int lane = t & 63;
  const int m16 = lane & 15;   // MFMA A row / B col / C col
  const int quad = lane >> 4;  // C/D row group

  // --- inhale block's bitmask: 16 rows x 64 words = 4KB ---
  {
    int word = t & 63, wv = t >> 6;
#pragma unroll
    for (int i = 0; i < 4; ++i) {
      int row = wv * 4 + i;
      bm_t[word][row] = bm32[(((size_t)(n * LL + l0 + row)) << 6) + word];
    }
  }

  // Q A-frags (shared by all col-tiles): A[m=m16][k=quad*8+j]
  const __bf16* qrow = Qb + ((size_t)(n * LL + l0 + m16)) * DD;
  bf16x8 aq0 = *(const bf16x8*)(qrow + quad * 8);
  bf16x8 aq1 = *(const bf16x8*)(qrow + 32 + quad * 8);

  const __bf16* kbase = Kb + (size_t)n * SS * DD;
  const __bf16* vbase = Vt + (size_t)n * DD * SS;
  const size_t mrow_base = ((size_t)(n * LL + l0)) * SS;
  const int sbase = w * STRIP;

  f32x4 acc_o[4] = {{0.f, 0.f, 0.f, 0.f}, {0.f, 0.f, 0.f, 0.f},
                    {0.f, 0.f, 0.f, 0.f}, {0.f, 0.f, 0.f, 0.f}};
  float rsum[4] = {0.f, 0.f, 0.f, 0.f};

  __syncthreads();  // bm_t ready

  // ================= pass A: barrier-free =================
  for (int c = 0; c < STRIP / 64; ++c) {
    const int s0 = sbase + c * 64;
    // --- QK^T: 16 rows x 64 s-cols = 4 col-tiles x 2 k-steps ---
    f32x4 acc[4];
#pragma unroll
    for (int ct = 0; ct < 4; ++ct) {
      const __bf16* krow = kbase + (size_t)(s0 + ct * 16 + m16) * DD;
      bf16x8 kb0 = *(const bf16x8*)(krow + quad * 8);
      bf16x8 kb1 = *(const bf16x8*)(krow + 32 + quad * 8);
      f32x4 a = {0.f, 0.f, 0.f, 0.f};
      a = __builtin_amdgcn_mfma_f32_16x16x32_bf16(aq0, kb0, a, 0, 0, 0);
      a = __builtin_amdgcn_mfma_f32_16x16x32_bf16(aq1, kb1, a, 0, 0, 0);
      acc[ct] = a;
    }
    // --- mask bits, exp, rowsum, stash bf16 e (wave-private) ---
    const int bw = s0 >> 5;  // word index [0,64)
    const uint4 mw0 = *(const uint4*)&bm_t[bw][quad * 4];
    const uint4 mw1 = *(const uint4*)&bm_t[bw + 1][quad * 4];
#pragma unroll
    for (int ct = 0; ct < 4; ++ct) {
      const unsigned sh = (unsigned)((ct * 16 + m16) & 31);
#pragma unroll
      for (int r = 0; r < 4; ++r) {
        unsigned wd = (ct < 2) ? (&mw0.x)[r] : (&mw1.x)[r];
        unsigned mk = (wd >> sh) & 1u;
        float e = mk ? __expf(acc[ct][r]) : 0.0f;
        rsum[r] += e;
        e_lds[w][c & 1][quad * 4 + r][ct * 16 + m16] = (__bf16)e;
      }
    }
    // --- PV: O[16x64] += E[16x64] @ V[64x64]; A wave-private LDS, B from Vt ---
    bf16x8 ae0 = *(const bf16x8*)(&e_lds[w][c & 1][m16][quad * 8]);
    bf16x8 ae1 = *(const bf16x8*)(&e_lds[w][c & 1][m16][32 + quad * 8]);
#pragma unroll
    for (int vt = 0; vt < 4; ++vt) {
      const __bf16* vrow = vbase + (size_t)(vt * 16 + m16) * SS + s0;
      bf16x8 vb0 = *(const bf16x8*)(vrow + quad * 8);
      bf16x8 vb1 = *(const bf16x8*)(vrow + 32 + quad * 8);
      acc_o[vt] = __builtin_amdgcn_mfma_f32_16x16x32_bf16(ae0, vb0, acc_o[vt], 0, 0, 0);
      acc_o[vt] = __builtin_amdgcn_mfma_f32_16x16x32_bf16(ae1, vb1, acc_o[vt], 0, 0, 0);
    }
  }

  // --- reduce rsum over the 16 cols this lane group saw (m16 dimension) ---
#pragma unroll
  for (int r = 0; r < 4; ++r) {
    float s = rsum[r];
    s += __shfl_xor(s, 1);
    s += __shfl_xor(s, 2);
    s += __shfl_xor(s, 4);
    s += __shfl_xor(s, 8);
    rsum[r] = s;
  }

  __syncthreads();  // all e_lds reads done before o_lds writes (alias)

  // --- publish per-strip partials ---
#pragma unroll
  for (int vt = 0; vt < 4; ++vt)
#pragma unroll
    for (int r = 0; r < 4; ++r) o_lds[w][quad * 4 + r][vt * 16 + m16] = acc_o[vt][r];
  if (m16 == 0) {
#pragma unroll
    for (int r = 0; r < 4; ++r) rs_lds[w][quad * 4 + r] = rsum[r];
  }
  __syncthreads();

  // --- combine: inv per row; wave w writes v-cols [16w,16w+16) of out_val ---
  float inv[4];
#pragma unroll
  for (int r = 0; r < 4; ++r) {
    int row = quad * 4 + r;
    float s = rs_lds[0][row] + rs_lds[1][row] + rs_lds[2][row] + rs_lds[3][row];
    inv[r] = 1.0f / s;
  }
#pragma unroll
  for (int r = 0; r < 4; ++r) {
    int row = quad * 4 + r;
    float o = o_lds[0][row][16 * w + m16] + o_lds[1][row][16 * w + m16] +
              o_lds[2][row][16 * w + m16] + o_lds[3][row][16 * w + m16];
    out_val[((size_t)(n * LL + l0 + row)) * DD + 16 * w + m16] = o * inv[r];
  }

  // ================= pass B: recompute, scale, store (barrier-free) =========
  for (int c = 0; c < STRIP / 64; ++c) {
    const int s0 = sbase + c * 64;
    f32x4 acc[4];
#pragma unroll
    for (int ct = 0; ct < 4; ++ct) {
      const __bf16* krow = kbase + (size_t)(s0 + ct * 16 + m16) * DD;
      bf16x8 kb0 = *(const bf16x8*)(krow + quad * 8);
      bf16x8 kb1 = *(const bf16x8*)(krow + 32 + quad * 8);
      f32x4 a = {0.f, 0.f, 0.f, 0.f};
      a = __builtin_amdgcn_mfma_f32_16x16x32_bf16(aq0, kb0, a, 0, 0, 0);
      a = __builtin_amdgcn_mfma_f32_16x16x32_bf16(aq1, kb1, a, 0, 0, 0);
      acc[ct] = a;
    }
    const int bw = s0 >> 5;
    const uint4 mw0 = *(const uint4*)&bm_t[bw][quad * 4];
    const uint4 mw1 = *(const uint4*)&bm_t[bw + 1][quad * 4];
#pragma unroll
    for (int ct = 0; ct < 4; ++ct) {
      const unsigned sh = (unsigned)((ct * 16 + m16) & 31);
#pragma unroll
      for (int r = 0; r < 4; ++r) {
        unsigned wd = (ct < 2) ? (&mw0.x)[r] : (&mw1.x)[r];
        unsigned mk = (wd >> sh) & 1u;
        float val = mk ? __expf(acc[ct][r]) * inv[r] : 0.0f;
        out_score[mrow_base + (size_t)(quad * 4 + r) * SS + s0 + ct * 16 + m16] = val;
      }
    }
  }
}

extern "C" void kernel_launch(void* const* d_in, const int* in_sizes, int n_in,
                              void* d_out, int out_size, void* d_ws, size_t ws_size,
                              hipStream_t stream) {
  const float* q = (const float*)d_in[0];
  const float* k = (const float*)d_in[1];
  const float* v = (const float*)d_in[2];
  const int* mask = (const int*)d_in[3];  // bool materialized as int32

  float* out_val = (float*)d_out;                     // [8,2048,64]
  float* out_score = out_val + (size_t)NB * LL * DD;  // [8,2048,2048]

  __bf16* Qb = (__bf16*)d_ws;                              // 2 MB
  __bf16* Kb = Qb + (size_t)NB * LL * DD;                  // 2 MB
  __bf16* Vt = Kb + (size_t)NB * SS * DD;                  // 2 MB
  unsigned long long* bm = (unsigned long long*)(Vt + (size_t)NB * DD * SS);  // 4 MB

  pack_mask<<<dim3(32768), dim3(256), 0, stream>>>(mask, bm);
  prep_norm<<<dim3((NB * LL * 2) / 4), dim3(256), 0, stream>>>(q, k, Qb, Kb);
  prep_vt<<<dim3(SS / 64, NB), dim3(256), 0, stream>>>(v, Vt);
  attn_main<<<dim3(LL / 16, NB), dim3(256), 0, stream>>>(Qb, Kb, Vt, (const unsigned*)bm,
                                                         out_val, out_score);
}